// Round 7
// baseline (46.174 us; speedup 1.0000x reference)
//
#include <hip/hip_runtime.h>
#include <math.h>

// N=16384, D=64, C=64.
// loss = 1 - (1/n_unique) * sum_c [ (||S_c||^2 - n_c) / (n_c (n_c - 1)) ]
// where S_c = sum of row-normalized feature rows of class c.
//
// 2 graph nodes:
//   memset(16.6 KB): zero acc[64*64] + cnt[64] + arrival counter
//   cpl_fused (128 blk x 512 thr): float4 phase1 -> LDS class matrix ->
//     device-atomic flush -> last-arriving block computes the scalar in-place.

#define NCLS 64
#define DIM 64
#define NB 128
#define THREADS 512
#define ROWS_PER_BLOCK 128            // 16384 / NB
#define ACC_FLOATS (NCLS * DIM + NCLS)   // acc + cnt
#define WS_BYTES ((ACC_FLOATS + 1) * 4)  // + counter

__global__ __launch_bounds__(THREADS) void cpl_fused(
    const float* __restrict__ feat,   // [n, DIM]
    const int* __restrict__ pred,     // [n]
    float* __restrict__ acc,          // [NCLS*DIM], pre-zeroed
    float* __restrict__ cnt,          // [NCLS], pre-zeroed
    unsigned* __restrict__ counter,   // [1], pre-zeroed
    float* __restrict__ out,          // [1]
    int n)
{
    __shared__ float s_acc[NCLS * DIM];
    __shared__ float s_cnt[NCLS];
    __shared__ int s_last;
    const int tid = threadIdx.x;

    for (int i = tid; i < NCLS * DIM; i += THREADS) s_acc[i] = 0.0f;
    if (tid < NCLS) s_cnt[tid] = 0.0f;
    __syncthreads();

    const int lane = tid & 63;
    const int wave = tid >> 6;                         // 0..7
    const int rpw  = ROWS_PER_BLOCK / (THREADS / 64);  // 16 rows per wave
    const int row0 = blockIdx.x * ROWS_PER_BLOCK + wave * rpw;
    const int g = lane >> 4;                           // row subgroup 0..3
    const int q = lane & 15;                           // dim quad 0..15

    #pragma unroll
    for (int it = 0; it < rpw / 4; ++it) {
        const int rbase = row0 + it * 4;               // wave covers 4 rows
        if (rbase + 3 < n) {
            // lane l -> row rbase+g, dims 4q..4q+3 (one dwordx4, coalesced)
            float4 v = *(const float4*)(feat + (size_t)rbase * DIM + lane * 4);
            float s = v.x * v.x + v.y * v.y + v.z * v.z + v.w * v.w;
            s += __shfl_xor(s, 1, 64);                 // 16-lane group reduce
            s += __shfl_xor(s, 2, 64);
            s += __shfl_xor(s, 4, 64);
            s += __shfl_xor(s, 8, 64);
            float r = rsqrtf(s);
            int c = pred[rbase + g];                   // group-uniform
            float* dst = &s_acc[c * DIM + q * 4];
            atomicAdd(dst + 0, v.x * r);
            atomicAdd(dst + 1, v.y * r);
            atomicAdd(dst + 2, v.z * r);
            atomicAdd(dst + 3, v.w * r);
            if (q == 0) atomicAdd(&s_cnt[c], 1.0f);
        } else {
            for (int r2 = rbase; r2 < rbase + 4 && r2 < n; ++r2) {
                float x = feat[(size_t)r2 * DIM + lane];
                float s = x * x;
                #pragma unroll
                for (int off = 32; off; off >>= 1) s += __shfl_xor(s, off, 64);
                float vv = x * rsqrtf(s);
                int c = pred[r2];
                atomicAdd(&s_acc[c * DIM + lane], vv);
                if (lane == 0) atomicAdd(&s_cnt[c], 1.0f);
            }
        }
    }
    __syncthreads();

    // Flush block-local sums to global accumulator (device-scope atomics).
    for (int i = tid; i < NCLS * DIM; i += THREADS) {
        float v = s_acc[i];
        if (v != 0.0f) atomicAdd(&acc[i], v);
    }
    if (tid < NCLS) {
        float v = s_cnt[tid];
        if (v != 0.0f) atomicAdd(&cnt[tid], v);
    }

    // Last-arriving block becomes the finisher.
    __threadfence();                                   // release our flushes
    if (tid == 0) {
        unsigned old = __hip_atomic_fetch_add(counter, 1u, __ATOMIC_ACQ_REL,
                                              __HIP_MEMORY_SCOPE_AGENT);
        s_last = (old == NB - 1);
    }
    __syncthreads();
    if (!s_last) return;
    __threadfence();                                   // acquire all flushes

    // ---- finish: 8 threads per class over the 16 KB accumulator ----
    __shared__ float s_avg[NCLS];
    __shared__ float s_pres[NCLS];
    const int c = tid >> 3;            // class 0..63
    const int part = tid & 7;          // 8 dims each
    float s = 0.0f;
    #pragma unroll
    for (int k = 0; k < 8; ++k) {
        float v = __hip_atomic_load(&acc[c * DIM + part * 8 + k],
                                    __ATOMIC_RELAXED, __HIP_MEMORY_SCOPE_AGENT);
        s += v * v;
    }
    s += __shfl_xor(s, 1, 64);
    s += __shfl_xor(s, 2, 64);
    s += __shfl_xor(s, 4, 64);
    if (part == 0) {
        float nc = __hip_atomic_load(&cnt[c], __ATOMIC_RELAXED,
                                     __HIP_MEMORY_SCOPE_AGENT);
        s_avg[c]  = (nc > 1.5f) ? (s - nc) / (nc * (nc - 1.0f)) : 0.0f;
        s_pres[c] = (nc > 0.5f) ? 1.0f : 0.0f;
    }
    __syncthreads();
    if (tid < 64) {
        float a  = s_avg[tid];
        float pr = s_pres[tid];
        #pragma unroll
        for (int off = 32; off; off >>= 1) {
            a  += __shfl_xor(a, off, 64);
            pr += __shfl_xor(pr, off, 64);
        }
        if (tid == 0) out[0] = 1.0f - a / pr;
    }
}

extern "C" void kernel_launch(void* const* d_in, const int* in_sizes, int n_in,
                              void* d_out, int out_size, void* d_ws, size_t ws_size,
                              hipStream_t stream) {
    const float* feat = (const float*)d_in[0];
    const int*   pred = (const int*)d_in[1];
    float* out = (float*)d_out;
    const int n = in_sizes[1];                 // 16384

    float*    acc     = (float*)d_ws;                  // NCLS*DIM
    float*    cnt     = acc + NCLS * DIM;              // NCLS
    unsigned* counter = (unsigned*)(cnt + NCLS);       // 1

    hipMemsetAsync(d_ws, 0, WS_BYTES, stream);
    cpl_fused<<<NB, THREADS, 0, stream>>>(feat, pred, acc, cnt, counter, out, n);
}

// Round 8
// 35.961 us; speedup vs baseline: 1.2840x; 1.2840x over previous
//
#include <hip/hip_runtime.h>
#include <math.h>

// N=16384, D=64, C=64.
// loss = 1 - (1/n_unique) * sum_c [ (||S_c||^2 - n_c) / (n_c (n_c - 1)) ]
// where S_c = sum of row-normalized feature rows of class c.
//
// 3 graph nodes (measured-best topology, R6 = 27.4 us):
//   memset(16.6 KB)  : zero acc[64*64] + cnt[64]
//   phase1 (64 x 1024): float4-vectorized normalize + LDS class accumulate,
//                       then device-atomic flush (halved vs R6: 64 blocks)
//   finish (1 x 256) : ||S_c||^2 -> per-class avg -> scalar loss.

#define NCLS 64
#define DIM 64
#define NB 64
#define THREADS 1024
#define ROWS_PER_BLOCK 256            // 16384 / NB
#define ACC_FLOATS (NCLS * DIM + NCLS)

__global__ __launch_bounds__(THREADS) void cpl_phase1(
    const float* __restrict__ feat,   // [n, DIM]
    const int* __restrict__ pred,     // [n]
    float* __restrict__ acc,          // [NCLS*DIM], pre-zeroed
    float* __restrict__ cnt,          // [NCLS], pre-zeroed
    int n)
{
    __shared__ float s_acc[NCLS * DIM];
    __shared__ float s_cnt[NCLS];
    const int tid = threadIdx.x;

    for (int i = tid; i < NCLS * DIM; i += THREADS) s_acc[i] = 0.0f;
    if (tid < NCLS) s_cnt[tid] = 0.0f;
    __syncthreads();

    const int lane = tid & 63;
    const int wave = tid >> 6;                         // 0..15
    const int rpw  = ROWS_PER_BLOCK / (THREADS / 64);  // 16 rows per wave
    const int row0 = blockIdx.x * ROWS_PER_BLOCK + wave * rpw;
    const int g = lane >> 4;                           // row subgroup 0..3
    const int q = lane & 15;                           // dim quad 0..15

    #pragma unroll
    for (int it = 0; it < rpw / 4; ++it) {             // 4 float4 iterations
        const int rbase = row0 + it * 4;               // wave covers 4 rows
        if (rbase + 3 < n) {
            // lane l -> row rbase+g, dims 4q..4q+3 (one dwordx4, coalesced)
            float4 v = *(const float4*)(feat + (size_t)rbase * DIM + lane * 4);
            float s = v.x * v.x + v.y * v.y + v.z * v.z + v.w * v.w;
            s += __shfl_xor(s, 1, 64);                 // 16-lane group reduce
            s += __shfl_xor(s, 2, 64);
            s += __shfl_xor(s, 4, 64);
            s += __shfl_xor(s, 8, 64);
            float r = rsqrtf(s);
            int c = pred[rbase + g];                   // group-uniform
            float* dst = &s_acc[c * DIM + q * 4];
            atomicAdd(dst + 0, v.x * r);
            atomicAdd(dst + 1, v.y * r);
            atomicAdd(dst + 2, v.z * r);
            atomicAdd(dst + 3, v.w * r);
            if (q == 0) atomicAdd(&s_cnt[c], 1.0f);
        } else {
            // tail fallback (never taken for n=16384)
            for (int r2 = rbase; r2 < rbase + 4 && r2 < n; ++r2) {
                float x = feat[(size_t)r2 * DIM + lane];
                float s = x * x;
                #pragma unroll
                for (int off = 32; off; off >>= 1) s += __shfl_xor(s, off, 64);
                float vv = x * rsqrtf(s);
                int c = pred[r2];
                atomicAdd(&s_acc[c * DIM + lane], vv);
                if (lane == 0) atomicAdd(&s_cnt[c], 1.0f);
            }
        }
    }
    __syncthreads();

    // Flush block-local sums (at 256 rows/block ~98% of slots are nonzero:
    // unconditional flush, no branch).
    for (int i = tid; i < NCLS * DIM; i += THREADS)
        atomicAdd(&acc[i], s_acc[i]);
    if (tid < NCLS) {
        float v = s_cnt[tid];
        if (v != 0.0f) atomicAdd(&cnt[tid], v);
    }
}

__global__ __launch_bounds__(256) void cpl_finish(
    const float* __restrict__ acc,   // [NCLS*DIM]
    const float* __restrict__ cnt,   // [NCLS]
    float* __restrict__ out)         // [1]
{
    __shared__ float s_avg[NCLS];
    __shared__ float s_pres[NCLS];
    const int t = threadIdx.x;
    const int c = t >> 2;            // 4 threads per class
    const int part = t & 3;

    const float4* src = (const float4*)(acc + c * DIM + part * 16);
    float s = 0.0f;
    #pragma unroll
    for (int k = 0; k < 4; ++k) {
        float4 v = src[k];
        s += v.x * v.x + v.y * v.y + v.z * v.z + v.w * v.w;
    }
    s += __shfl_xor(s, 1, 64);
    s += __shfl_xor(s, 2, 64);
    if (part == 0) {
        float nc = cnt[c];
        s_avg[c]  = (nc > 1.5f) ? (s - nc) / (nc * (nc - 1.0f)) : 0.0f;
        s_pres[c] = (nc > 0.5f) ? 1.0f : 0.0f;
    }
    __syncthreads();
    if (t < 64) {
        float a  = s_avg[t];
        float pr = s_pres[t];
        #pragma unroll
        for (int off = 32; off; off >>= 1) {
            a  += __shfl_xor(a, off, 64);
            pr += __shfl_xor(pr, off, 64);
        }
        if (t == 0) out[0] = 1.0f - a / pr;
    }
}

extern "C" void kernel_launch(void* const* d_in, const int* in_sizes, int n_in,
                              void* d_out, int out_size, void* d_ws, size_t ws_size,
                              hipStream_t stream) {
    const float* feat = (const float*)d_in[0];
    const int*   pred = (const int*)d_in[1];
    float* out = (float*)d_out;
    const int n = in_sizes[1];                 // 16384

    float* acc = (float*)d_ws;                 // NCLS*DIM floats
    float* cnt = acc + NCLS * DIM;             // NCLS floats

    hipMemsetAsync(d_ws, 0, ACC_FLOATS * sizeof(float), stream);
    cpl_phase1<<<NB, THREADS, 0, stream>>>(feat, pred, acc, cnt, n);
    cpl_finish<<<1, 256, 0, stream>>>(acc, cnt, out);
}

// Round 9
// 30.858 us; speedup vs baseline: 1.4963x; 1.1654x over previous
//
#include <hip/hip_runtime.h>
#include <math.h>

// N=16384, D=64, C=64.
// loss = 1 - (1/n_unique) * sum_c [ (||S_c||^2 - n_c) / (n_c (n_c - 1)) ]
// where S_c = sum of row-normalized feature rows of class c.
//
// 2 graph nodes:
//   memset(16.6 KB): zero acc[64*64] + cnt[64] + arrival counter
//   cpl_fused (128 blk x 512 thr, R6-best shape): float4 phase1 -> LDS class
//     matrix -> device-atomic flush -> last-arriving block finishes in-place.
// NO __threadfence: __syncthreads drains vmcnt (atomics globally performed),
// the ACQ_REL arrival fetch_add provides the release/acquire chain, and the
// finisher reads acc with agent-scope atomic loads.

#define NCLS 64
#define DIM 64
#define NB 128
#define THREADS 512
#define ROWS_PER_BLOCK 128            // 16384 / NB
#define ACC_FLOATS (NCLS * DIM + NCLS)   // acc + cnt
#define WS_BYTES ((ACC_FLOATS + 1) * 4)  // + counter

__global__ __launch_bounds__(THREADS) void cpl_fused(
    const float* __restrict__ feat,   // [n, DIM]
    const int* __restrict__ pred,     // [n]
    float* __restrict__ acc,          // [NCLS*DIM], pre-zeroed
    float* __restrict__ cnt,          // [NCLS], pre-zeroed
    unsigned* __restrict__ counter,   // [1], pre-zeroed
    float* __restrict__ out,          // [1]
    int n)
{
    __shared__ float s_acc[NCLS * DIM];
    __shared__ float s_cnt[NCLS];
    __shared__ int s_last;
    const int tid = threadIdx.x;

    for (int i = tid; i < NCLS * DIM; i += THREADS) s_acc[i] = 0.0f;
    if (tid < NCLS) s_cnt[tid] = 0.0f;
    __syncthreads();

    const int lane = tid & 63;
    const int wave = tid >> 6;                         // 0..7
    const int rpw  = ROWS_PER_BLOCK / (THREADS / 64);  // 16 rows per wave
    const int row0 = blockIdx.x * ROWS_PER_BLOCK + wave * rpw;
    const int g = lane >> 4;                           // row subgroup 0..3
    const int q = lane & 15;                           // dim quad 0..15

    #pragma unroll
    for (int it = 0; it < rpw / 4; ++it) {
        const int rbase = row0 + it * 4;               // wave covers 4 rows
        if (rbase + 3 < n) {
            // lane l -> row rbase+g, dims 4q..4q+3 (one dwordx4, coalesced)
            float4 v = *(const float4*)(feat + (size_t)rbase * DIM + lane * 4);
            float s = v.x * v.x + v.y * v.y + v.z * v.z + v.w * v.w;
            s += __shfl_xor(s, 1, 64);                 // 16-lane group reduce
            s += __shfl_xor(s, 2, 64);
            s += __shfl_xor(s, 4, 64);
            s += __shfl_xor(s, 8, 64);
            float r = rsqrtf(s);
            int c = pred[rbase + g];                   // group-uniform
            float* dst = &s_acc[c * DIM + q * 4];
            atomicAdd(dst + 0, v.x * r);
            atomicAdd(dst + 1, v.y * r);
            atomicAdd(dst + 2, v.z * r);
            atomicAdd(dst + 3, v.w * r);
            if (q == 0) atomicAdd(&s_cnt[c], 1.0f);
        } else {
            for (int r2 = rbase; r2 < rbase + 4 && r2 < n; ++r2) {
                float x = feat[(size_t)r2 * DIM + lane];
                float s = x * x;
                #pragma unroll
                for (int off = 32; off; off >>= 1) s += __shfl_xor(s, off, 64);
                float vv = x * rsqrtf(s);
                int c = pred[r2];
                atomicAdd(&s_acc[c * DIM + lane], vv);
                if (lane == 0) atomicAdd(&s_cnt[c], 1.0f);
            }
        }
    }
    __syncthreads();

    // Flush block-local sums to global accumulator (device-scope atomics).
    for (int i = tid; i < NCLS * DIM; i += THREADS) {
        float v = s_acc[i];
        if (v != 0.0f) atomicAdd(&acc[i], v);
    }
    if (tid < NCLS) {
        float v = s_cnt[tid];
        if (v != 0.0f) atomicAdd(&cnt[tid], v);
    }

    // __syncthreads drains vmcnt -> all this block's atomics are globally
    // performed before tid 0 bumps the arrival counter (release).
    __syncthreads();
    if (tid == 0) {
        unsigned old = __hip_atomic_fetch_add(counter, 1u, __ATOMIC_ACQ_REL,
                                              __HIP_MEMORY_SCOPE_AGENT);
        s_last = (old == NB - 1);
    }
    __syncthreads();
    if (!s_last) return;

    // ---- finisher (last-arriving block): 8 threads per class ----
    __shared__ float s_avg[NCLS];
    __shared__ float s_pres[NCLS];
    const int c = tid >> 3;            // class 0..63
    const int part = tid & 7;          // 8 dims each
    float s = 0.0f;
    #pragma unroll
    for (int k = 0; k < 8; ++k) {
        float v = __hip_atomic_load(&acc[c * DIM + part * 8 + k],
                                    __ATOMIC_RELAXED, __HIP_MEMORY_SCOPE_AGENT);
        s += v * v;
    }
    s += __shfl_xor(s, 1, 64);
    s += __shfl_xor(s, 2, 64);
    s += __shfl_xor(s, 4, 64);
    if (part == 0) {
        float nc = __hip_atomic_load(&cnt[c], __ATOMIC_RELAXED,
                                     __HIP_MEMORY_SCOPE_AGENT);
        s_avg[c]  = (nc > 1.5f) ? (s - nc) / (nc * (nc - 1.0f)) : 0.0f;
        s_pres[c] = (nc > 0.5f) ? 1.0f : 0.0f;
    }
    __syncthreads();
    if (tid < 64) {
        float a  = s_avg[tid];
        float pr = s_pres[tid];
        #pragma unroll
        for (int off = 32; off; off >>= 1) {
            a  += __shfl_xor(a, off, 64);
            pr += __shfl_xor(pr, off, 64);
        }
        if (tid == 0) out[0] = 1.0f - a / pr;
    }
}

extern "C" void kernel_launch(void* const* d_in, const int* in_sizes, int n_in,
                              void* d_out, int out_size, void* d_ws, size_t ws_size,
                              hipStream_t stream) {
    const float* feat = (const float*)d_in[0];
    const int*   pred = (const int*)d_in[1];
    float* out = (float*)d_out;
    const int n = in_sizes[1];                 // 16384

    float*    acc     = (float*)d_ws;                  // NCLS*DIM
    float*    cnt     = acc + NCLS * DIM;              // NCLS
    unsigned* counter = (unsigned*)(cnt + NCLS);       // 1

    hipMemsetAsync(d_ws, 0, WS_BYTES, stream);
    cpl_fused<<<NB, THREADS, 0, stream>>>(feat, pred, acc, cnt, counter, out, n);
}

// Round 10
// 27.339 us; speedup vs baseline: 1.6889x; 1.1287x over previous
//
#include <hip/hip_runtime.h>
#include <math.h>

// N=16384, D=64, C=64.
// loss = 1 - (1/n_unique) * sum_c [ (||S_c||^2 - n_c) / (n_c (n_c - 1)) ]
// where S_c = sum of row-normalized feature rows of class c.
//
// 2 graph nodes, NO memset, NO global atomics on the hot path:
//   phase1 (128 blk x 512 thr): float4 normalize + LDS class accumulate,
//     write block-private partial [blk][64*64] + cntp [blk][64] (fully
//     written every call -> no init, replay-deterministic).
//   finish (16 blk x 256 thr): block k owns classes 4k..4k+3 (256 contiguous
//     columns), coalesced column-reduce over 128 partials, wave-reduce
//     ||S_c||^2, write 8-float slot; last-arriving block (counter mod 16,
//     works for ANY persistent counter value) folds 64 slots -> scalar.

#define NCLS 64
#define DIM 64
#define NB 128
#define THREADS 512
#define ROWS_PER_BLOCK 128            // 16384 / NB
#define FB 16                         // finish blocks

__global__ __launch_bounds__(THREADS) void cpl_phase1(
    const float* __restrict__ feat,   // [n, DIM]
    const int* __restrict__ pred,     // [n]
    float* __restrict__ partial,      // [NB, NCLS*DIM]
    float* __restrict__ cntp,         // [NB, NCLS]
    int n)
{
    __shared__ float s_acc[NCLS * DIM];
    __shared__ float s_cnt[NCLS];
    const int tid = threadIdx.x;

    for (int i = tid; i < NCLS * DIM; i += THREADS) s_acc[i] = 0.0f;
    if (tid < NCLS) s_cnt[tid] = 0.0f;
    __syncthreads();

    const int lane = tid & 63;
    const int wave = tid >> 6;                         // 0..7
    const int rpw  = ROWS_PER_BLOCK / (THREADS / 64);  // 16 rows per wave
    const int row0 = blockIdx.x * ROWS_PER_BLOCK + wave * rpw;
    const int g = lane >> 4;                           // row subgroup 0..3
    const int q = lane & 15;                           // dim quad 0..15

    #pragma unroll
    for (int it = 0; it < rpw / 4; ++it) {
        const int rbase = row0 + it * 4;               // wave covers 4 rows
        if (rbase + 3 < n) {
            float4 v = *(const float4*)(feat + (size_t)rbase * DIM + lane * 4);
            float s = v.x * v.x + v.y * v.y + v.z * v.z + v.w * v.w;
            s += __shfl_xor(s, 1, 64);
            s += __shfl_xor(s, 2, 64);
            s += __shfl_xor(s, 4, 64);
            s += __shfl_xor(s, 8, 64);
            float r = rsqrtf(s);
            int c = pred[rbase + g];                   // group-uniform
            float* dst = &s_acc[c * DIM + q * 4];
            atomicAdd(dst + 0, v.x * r);
            atomicAdd(dst + 1, v.y * r);
            atomicAdd(dst + 2, v.z * r);
            atomicAdd(dst + 3, v.w * r);
            if (q == 0) atomicAdd(&s_cnt[c], 1.0f);
        } else {
            for (int r2 = rbase; r2 < rbase + 4 && r2 < n; ++r2) {
                float x = feat[(size_t)r2 * DIM + lane];
                float s = x * x;
                #pragma unroll
                for (int off = 32; off; off >>= 1) s += __shfl_xor(s, off, 64);
                float vv = x * rsqrtf(s);
                int c = pred[r2];
                atomicAdd(&s_acc[c * DIM + lane], vv);
                if (lane == 0) atomicAdd(&s_cnt[c], 1.0f);
            }
        }
    }
    __syncthreads();

    // Block-private partial (float4 stores, 2 per thread). Fully written.
    float4* p4 = (float4*)(partial + (size_t)blockIdx.x * (NCLS * DIM));
    const float4* s4 = (const float4*)s_acc;
    p4[tid]       = s4[tid];
    p4[tid + 512] = s4[tid + 512];
    if (tid < NCLS) cntp[blockIdx.x * NCLS + tid] = s_cnt[tid];
}

__global__ __launch_bounds__(256) void cpl_finish(
    const float* __restrict__ partial,  // [NB, NCLS*DIM]
    const float* __restrict__ cntp,     // [NB, NCLS]
    float* __restrict__ slots,          // [FB, 8] (avg,pres per class)
    unsigned* __restrict__ counter,     // [1], NEVER reset (mod-16 trick)
    float* __restrict__ out)            // [1]
{
    __shared__ int s_last;
    const int t = threadIdx.x;
    const int blk = blockIdx.x;         // 0..15
    const int lane = t & 63;
    const int w = t >> 6;               // wave 0..3 -> class blk*4 + w
    const int cls = blk * 4 + w;

    // Column sum: this thread owns column (blk*256 + t) of the [NB x 4096]
    // partial matrix. Adjacent threads -> adjacent addresses: coalesced.
    const int col = blk * 256 + t;
    float s = 0.0f;
    #pragma unroll 8
    for (int b = 0; b < NB; ++b)
        s += partial[(size_t)b * (NCLS * DIM) + col];

    // wave w holds class cls: lane = dim. ||S_c||^2 via wave reduce.
    float sq = s * s;
    sq += __shfl_xor(sq, 1, 64);
    sq += __shfl_xor(sq, 2, 64);
    sq += __shfl_xor(sq, 4, 64);
    sq += __shfl_xor(sq, 8, 64);
    sq += __shfl_xor(sq, 16, 64);
    sq += __shfl_xor(sq, 32, 64);

    // Class count: lane l sums 2 of the 128 cntp entries for cls.
    float c = cntp[(lane * 2) * NCLS + cls] + cntp[(lane * 2 + 1) * NCLS + cls];
    c += __shfl_xor(c, 1, 64);
    c += __shfl_xor(c, 2, 64);
    c += __shfl_xor(c, 4, 64);
    c += __shfl_xor(c, 8, 64);
    c += __shfl_xor(c, 16, 64);
    c += __shfl_xor(c, 32, 64);

    if (lane == 0) {
        float avg  = (c > 1.5f) ? (sq - c) / (c * (c - 1.0f)) : 0.0f;
        float pres = (c > 0.5f) ? 1.0f : 0.0f;
        __hip_atomic_store(&slots[blk * 8 + w * 2],     avg,
                           __ATOMIC_RELAXED, __HIP_MEMORY_SCOPE_AGENT);
        __hip_atomic_store(&slots[blk * 8 + w * 2 + 1], pres,
                           __ATOMIC_RELAXED, __HIP_MEMORY_SCOPE_AGENT);
    }

    // __syncthreads drains vmcnt; ACQ_REL RMW forms the release/acquire chain.
    __syncthreads();
    if (t == 0) {
        unsigned old = __hip_atomic_fetch_add(counter, 1u, __ATOMIC_ACQ_REL,
                                              __HIP_MEMORY_SCOPE_AGENT);
        s_last = ((old & (FB - 1)) == FB - 1);   // works for any start value
    }
    __syncthreads();
    if (!s_last) return;

    // Last block: 64 avg entries at even slots, 64 pres at odd.
    if (t < 64) {
        float a  = __hip_atomic_load(&slots[2 * t],     __ATOMIC_RELAXED,
                                     __HIP_MEMORY_SCOPE_AGENT);
        float pr = __hip_atomic_load(&slots[2 * t + 1], __ATOMIC_RELAXED,
                                     __HIP_MEMORY_SCOPE_AGENT);
        #pragma unroll
        for (int off = 32; off; off >>= 1) {
            a  += __shfl_xor(a, off, 64);
            pr += __shfl_xor(pr, off, 64);
        }
        if (t == 0) out[0] = 1.0f - a / pr;
    }
}

extern "C" void kernel_launch(void* const* d_in, const int* in_sizes, int n_in,
                              void* d_out, int out_size, void* d_ws, size_t ws_size,
                              hipStream_t stream) {
    const float* feat = (const float*)d_in[0];
    const int*   pred = (const int*)d_in[1];
    float* out = (float*)d_out;
    const int n = in_sizes[1];                 // 16384

    float*    partial = (float*)d_ws;                          // NB*4096
    float*    cntp    = partial + (size_t)NB * (NCLS * DIM);   // NB*64
    float*    slots   = cntp + NB * NCLS;                      // FB*8
    unsigned* counter = (unsigned*)(slots + FB * 8);           // 1, never reset

    cpl_phase1<<<NB, THREADS, 0, stream>>>(feat, pred, partial, cntp, n);
    cpl_finish<<<FB, 256, 0, stream>>>(partial, cntp, slots, counter, out);
}